// Round 14
// baseline (331.623 us; speedup 1.0000x reference)
//
#include <hip/hip_runtime.h>

// Problem constants
#define BATCH 4
#define NNODE 50000
#define NEDGE 1600000
#define F_IN 12
#define F_OUT 48
#define SEQ 12

#define BNODE 64                                // dst-nodes per bucket (pow2)
#define NBUCK ((NNODE + BNODE - 1) / BNODE)     // 782 buckets per batch
#define NBINS (BATCH * NBUCK)                   // 3128
#define SCAN_N 4096                             // padded single-block scan
#define EBLK 4096                               // edges per count/fill block
#define EPB_C (EBLK / 256)                      // 16 (count, 256 thr)
#define EPB_F (EBLK / 512)                      // 8  (fill, 512 thr)
#define NFB ((NEDGE + EBLK - 1) / EBLK)         // 391
#define CAPB 2560                               // per-bin record capacity (~mean+11sigma)
#define MAXR (CAPB / 256)                       // 10 records max per thread (sortdeg)

typedef float f4v __attribute__((ext_vector_type(4)));

// ---------- CSR build: two-level bucketing ----------

__global__ void __launch_bounds__(256) k_zero(int* __restrict__ cnt) {
    int i = blockIdx.x * 256 + threadIdx.x;
    if (i < SCAN_N) cnt[i] = 0;
}

__global__ void __launch_bounds__(256) k_count(const int* __restrict__ ei,
                                               int* __restrict__ cnt) {
    __shared__ int h[NBUCK];
    int t = threadIdx.x;
    for (int i = t; i < NBUCK; i += 256) h[i] = 0;
    __syncthreads();
    int b = blockIdx.y;
    int e0 = blockIdx.x * EBLK;
    const int* dsts = ei + ((size_t)b * 2 + 1) * NEDGE;
    for (int it = 0; it < EPB_C; ++it) {
        int e = e0 + it * 256 + t;
        if (e < NEDGE) atomicAdd(&h[dsts[e] >> 6], 1);
    }
    __syncthreads();
    for (int i = t; i < NBUCK; i += 256) {
        int c = h[i];
        if (c) atomicAdd(&cnt[b * NBUCK + i], c);
    }
}

__global__ void __launch_bounds__(256) k_scan(const int* __restrict__ cnt,
                                              int* __restrict__ off,
                                              int* __restrict__ cur) {
    __shared__ int w[256];
    int t = threadIdx.x;
    int base = t * 16;
    int loc[16];
    int s = 0;
#pragma unroll
    for (int j = 0; j < 16; j++) { loc[j] = cnt[base + j]; s += loc[j]; }
    w[t] = s;
    __syncthreads();
    for (int d = 1; d < 256; d <<= 1) {
        int v = (t >= d) ? w[t - d] : 0;
        __syncthreads();
        w[t] += v;
        __syncthreads();
    }
    int run = w[t] - s;
#pragma unroll
    for (int j = 0; j < 16; j++) {
        int i = base + j;
        off[i] = run;
        if (i < NBINS) cur[i] = run;
        run += loc[j];
    }
}

// 512 threads: 3 blocks/CU (LDS ~48KB) x 8 waves = 75% occupancy cap to hide
// rank-atomic latency. Key = (dst<<16)|src (full dst -> no sbuck array).
__global__ void __launch_bounds__(512) k_fill(const int* __restrict__ ei,
                                              const float* __restrict__ ew,
                                              int* __restrict__ cur,
                                              int2* __restrict__ rec) {
    __shared__ int h[1024];
    __shared__ int loff[1024];
    __shared__ int gbase[NBUCK];
    __shared__ int2 srec[EBLK];      // 32 KB
    __shared__ int w[512];

    int t = threadIdx.x;
    int b = blockIdx.y;
    int e0 = blockIdx.x * EBLK;
    for (int i = t; i < 1024; i += 512) h[i] = 0;
    __syncthreads();

    const size_t ebase = (size_t)b * 2 * NEDGE;
    const int* srcs = ei + ebase;
    const int* dsts = ei + ebase + NEDGE;
    const float* ws = ew + (size_t)b * NEDGE;

    int2 myrec[EPB_F];
    int mypk[EPB_F];
#pragma unroll
    for (int it = 0; it < EPB_F; ++it) {
        int e = e0 + it * 512 + t;
        int valid = e < NEDGE;
        int src = 0, dst = 0;
        float wv = 0.0f;
        if (valid) { src = srcs[e]; dst = dsts[e]; wv = ws[e]; }
        int g = dst >> 6;
        int r = 0;
        if (valid) r = atomicAdd(&h[g], 1);
        myrec[it] = make_int2((dst << 16) | src, __float_as_int(wv));
        mypk[it] = valid ? ((g << 16) | r) : -1;   // r < 4096 fits
    }
    __syncthreads();

    // scan 1024 bucket counts (2 per thread)
    int c0 = h[2 * t], c1 = h[2 * t + 1];
    int ls = c0 + c1;
    w[t] = ls;
    __syncthreads();
    for (int d = 1; d < 512; d <<= 1) {
        int v = (t >= d) ? w[t - d] : 0;
        __syncthreads();
        w[t] += v;
        __syncthreads();
    }
    int excl = w[t] - ls;
    loff[2 * t] = excl;
    loff[2 * t + 1] = excl + c0;
    __syncthreads();

    for (int i = t; i < NBUCK; i += 512) {
        int c = h[i];
        if (c) gbase[i] = atomicAdd(&cur[b * NBUCK + i], c);
    }
#pragma unroll
    for (int it = 0; it < EPB_F; ++it) {
        int pk = mypk[it];
        if (pk >= 0) {
            int g = pk >> 16, r = pk & 0xFFFF;
            srec[loff[g] + r] = myrec[it];
        }
    }
    __syncthreads();

    int nvalid = min(EBLK, NEDGE - e0);
    for (int j = t; j < nvalid; j += 512) {
        int2 rv = srec[j];
        int g = ((unsigned)rv.x) >> 22;          // dst>>6 (logical shift)
        rec[gbase[g] + (j - loff[g])] = rv;
    }
}

// ---------- numeric phase ----------

// Per bin: rank ONCE (int atomics), node-sort in LDS, write sorted records
// back to rec IN PLACE + per-node bases; compute deg in registers; write
// dinv AND the xs = dinv*x staging rows for this bucket's nodes.
__global__ void __launch_bounds__(256) k_sortdeg(const int* __restrict__ off,
                                                 int2* rec,
                                                 const float* __restrict__ x,
                                                 float* __restrict__ dinv,
                                                 float* __restrict__ xs,
                                                 int* __restrict__ nodebase) {
    __shared__ int2 srec[CAPB];      // 20.5 KB node-sorted records
    __shared__ int hh[BNODE];
    __shared__ int basev[BNODE];
    __shared__ int wsc[BNODE];

    int t = threadIdx.x;
    // same XCD mapping as k_gather2 so rec slice stays L2-warm
    int bid = blockIdx.x;
    int xcd = bid & 7;
    int b = xcd >> 1;
    int gl = ((bid >> 3) << 1) + (xcd & 1);   // 0..781, bijective
    int bin = b * NBUCK + gl;

    if (t < BNODE) hh[t] = 0;
    __syncthreads();

    int s = off[bin], e = off[bin + 1];
    const unsigned long long* rp = (const unsigned long long*)rec;

    // phase 1: load + rank by node
    int2 myrec[MAXR];
    int mypk[MAXR];
#pragma unroll
    for (int i = 0; i < MAXR; i++) {
        mypk[i] = -1;
        int j = s + i * 256 + t;
        if (j < e) {
            unsigned long long rv = rp[j];
            int key = (int)(rv & 0xFFFFFFFFull);
            myrec[i] = make_int2(key, (int)(rv >> 32));
            int node = (key >> 16) & 63;
            int r = atomicAdd(&hh[node], 1);
            mypk[i] = (r << 6) | node;
        }
    }
    __syncthreads();

    // phase 2: exclusive scan of 64 node counts
    if (t < BNODE) wsc[t] = hh[t];
    __syncthreads();
    for (int d = 1; d < BNODE; d <<= 1) {
        int v = 0;
        if (t < BNODE && t >= d) v = wsc[t - d];
        __syncthreads();
        if (t < BNODE) wsc[t] += v;
        __syncthreads();
    }
    if (t < BNODE) basev[t] = wsc[t] - hh[t];
    __syncthreads();

    // phase 3: scatter node-sorted into LDS
#pragma unroll
    for (int i = 0; i < MAXR; i++) {
        int pk = mypk[i];
        if (pk >= 0) srec[basev[pk & 63] + (pk >> 6)] = myrec[i];
    }
    __syncthreads();

    // phase 3b: sorted records back to global (in place) + per-node bases
    int cntr = e - s;
    for (int j = t; j < cntr; j += 256) rec[s + j] = srec[j];
    if (t < BNODE) nodebase[bin * BNODE + t] = s + basev[t];

    // phase 4: per-node deg in registers (4 threads/node)
    int node = t >> 2, par = t & 3;
    int rs = basev[node], cn = hh[node];
    float sum = 0.0f;
    for (int j = rs + par; j < rs + cn; j += 4)
        sum += __int_as_float(srec[j].y);
    sum += __shfl_xor(sum, 1);
    sum += __shfl_xor(sum, 2);
    float rsq = rsqrtf(1.0f + sum);           // +1 = self-loop weight

    int n = gl * BNODE + node;
    if (n >= NNODE) return;
    size_t gi = (size_t)b * NNODE + n;
    if (par == 0) dinv[gi] = rsq;
    // xs row: elements [par*4, par*4+4), pad (12..15) = 0
    f4v o = {0.f, 0.f, 0.f, 0.f};
    if (par < 3) {
        const f4v* x4 = (const f4v*)(x + gi * F_IN);
        f4v v = x4[par];
        o.x = rsq * v.x; o.y = rsq * v.y; o.z = rsq * v.z; o.w = rsq * v.w;
    }
    ((f4v*)xs)[gi * 4 + par] = o;
}

// Feature-split gather: 4 lanes/node, lane par owns features [4par,4par+4).
// Per record: ONE broadcast rec load + ONE xs line per group (was 3 lines).
__global__ void __launch_bounds__(256) k_gather2(const int* __restrict__ off,
                                                 const int2* __restrict__ rec,
                                                 const int* __restrict__ nodebase,
                                                 const float* __restrict__ xs,
                                                 const float* __restrict__ dinv,
                                                 const float* __restrict__ Wm,
                                                 const float* __restrict__ bias,
                                                 float* __restrict__ out) {
    __shared__ float sW[F_IN * F_OUT];
    __shared__ float sb[F_OUT];
    __shared__ int nb[BNODE + 1];

    int t = threadIdx.x;
    int bid = blockIdx.x;
    int xcd = bid & 7;
    int b = xcd >> 1;
    int gl = ((bid >> 3) << 1) + (xcd & 1);
    int bin = b * NBUCK + gl;

    for (int i = t; i < F_IN * F_OUT; i += 256) sW[i] = Wm[i];
    if (t < F_OUT) sb[t] = bias[t];
    if (t < BNODE) nb[t] = nodebase[bin * BNODE + t];
    if (t == 0) nb[BNODE] = off[bin + 1];
    __syncthreads();

    int node = t >> 2, par = t & 3;
    int rs = nb[node], re = nb[node + 1];
    const f4v* xs4 = (const f4v*)xs + (size_t)b * NNODE * 4;
    const unsigned long long* rp = (const unsigned long long*)rec;

    // acc = this lane's feature slice, accumulated over ALL records of node.
    f4v acc = {0.f, 0.f, 0.f, 0.f};
    int j = rs;
    for (; j + 2 <= re; j += 2) {               // 2-record unroll for ILP
        unsigned long long rv0 = __builtin_nontemporal_load(rp + j);
        unsigned long long rv1 = __builtin_nontemporal_load(rp + j + 1);
        if (par < 3) {
            int k0 = (int)(rv0 & 0xFFFFFFFFull);
            int k1 = (int)(rv1 & 0xFFFFFFFFull);
            float w0 = __int_as_float((int)(rv0 >> 32));
            float w1 = __int_as_float((int)(rv1 >> 32));
            f4v v0 = xs4[(size_t)(k0 & 0xFFFF) * 4 + par];
            f4v v1 = xs4[(size_t)(k1 & 0xFFFF) * 4 + par];
            acc += w0 * v0;
            acc += w1 * v1;
        }
    }
    if (j < re) {
        unsigned long long rv0 = __builtin_nontemporal_load(rp + j);
        if (par < 3) {
            int k0 = (int)(rv0 & 0xFFFFFFFFull);
            float w0 = __int_as_float((int)(rv0 >> 32));
            acc += w0 * xs4[(size_t)(k0 & 0xFFFF) * 4 + par];
        }
    }

    int n = gl * BNODE + node;
    float di = (n < NNODE) ? dinv[(size_t)b * NNODE + n] : 0.0f;
    // self term (xs = dinv*x folds the self-loop), then scale by di
    if (n < NNODE && par < 3) acc += xs4[(size_t)n * 4 + par];
    acc *= di;

    // broadcast the 3 feature slices across the 4-lane group
    int base = t & ~3;
    float a[F_IN];
#pragma unroll
    for (int k = 0; k < 3; k++) {
        a[4 * k + 0] = __shfl(acc.x, base + k);
        a[4 * k + 1] = __shfl(acc.y, base + k);
        a[4 * k + 2] = __shfl(acc.z, base + k);
        a[4 * k + 3] = __shfl(acc.w, base + k);
    }

    if (n >= NNODE) return;
    float hv[12];
#pragma unroll
    for (int jo = 0; jo < 12; jo++) {
        int jj = par * 12 + jo;
        float v = sb[jj];
#pragma unroll
        for (int k = 0; k < F_IN; k++) v = fmaf(a[k], sW[k * F_OUT + jj], v);
        hv[jo] = v;
    }
    f4v* out4 = (f4v*)out;
#pragma unroll
    for (int q = 0; q < 3; q++) {
        int sq = par * 3 + q;
        f4v v = {hv[q * 4 + 0], hv[q * 4 + 1], hv[q * 4 + 2], hv[q * 4 + 3]};
        __builtin_nontemporal_store(v, out4 + (size_t)(b * SEQ + sq) * NNODE + n);
    }
}

extern "C" void kernel_launch(void* const* d_in, const int* in_sizes, int n_in,
                              void* d_out, int out_size, void* d_ws, size_t ws_size,
                              hipStream_t stream) {
    const float* x  = (const float*)d_in[0];
    const int*   ei = (const int*)d_in[1];
    const float* ew = (const float*)d_in[2];
    const float* Wm = (const float*)d_in[3];
    const float* bv = (const float*)d_in[4];
    float* out = (float*)d_out;

    // Workspace: rec 51.2 | xs 12.8 | cnt/off/cur | dinv 0.8 | nodebase 0.8 MB
    int2*  rec = (int2*)d_ws;
    float* xs  = (float*)(rec + (size_t)BATCH * NEDGE);
    int*   cnt = (int*)(xs + (size_t)BATCH * NNODE * 16);
    int*   off = cnt + SCAN_N;
    int*   cur = off + SCAN_N;
    float* dinv = (float*)(cur + NBINS);
    int*   nodebase = (int*)(dinv + (size_t)BATCH * NNODE);

    k_zero<<<SCAN_N / 256, 256, 0, stream>>>(cnt);
    {
        dim3 grid(NFB, BATCH);
        k_count<<<grid, 256, 0, stream>>>(ei, cnt);
    }
    k_scan<<<1, 256, 0, stream>>>(cnt, off, cur);
    {
        dim3 grid(NFB, BATCH);
        k_fill<<<grid, 512, 0, stream>>>(ei, ew, cur, rec);
    }
    k_sortdeg<<<8 * (NBUCK / 2), 256, 0, stream>>>(off, rec, x, dinv, xs, nodebase);
    k_gather2<<<8 * (NBUCK / 2), 256, 0, stream>>>(off, rec, nodebase, xs, dinv, Wm, bv, out);
}